// Round 5
// baseline (1031.073 us; speedup 1.0000x reference)
//
#include <hip/hip_runtime.h>
#include <hip/hip_bf16.h>

#define NB 16384
#define DIM 32
#define LS 100
#define KH 50
#define PCOLS 9696           // 3*DIM*LS + 3*DIM
#define LPAD 112             // LS padded to 7*16
#define DSTRIDE 352          // 3*LPAD + 16 tail slots (bias2, eps, alpha, 13 zero)
#define NCR (DIM * DSTRIDE)  // 11264 reordered columns
#define KPAD 64              // 50 real + 1 bias row + 13 zero
#define PREPB (NCR / 64)     // 176 prep blocks per subnet

typedef __attribute__((ext_vector_type(4))) float f32x4;
typedef __attribute__((ext_vector_type(8))) short short8;

static __device__ __forceinline__ unsigned short f2bf(float f) {
    __hip_bfloat16 h = __float2bfloat16(f);
    return *reinterpret_cast<unsigned short*>(&h);
}

// ---- reorder + pad + bf16-ify W2 (b2 folded as k=50 row), linear k layout ----
// W2R[row][k], row = d*352 + q; q<336: q=t*112+l (orig col t*3200+d*100+l);
// q in 336..338: tail cols 9600/9632/9664 + d (bias2, eps, alpha); rest zero.
static __device__ __forceinline__ void prep_body(int bx, const float* __restrict__ W2,
                                                 const float* __restrict__ b2,
                                                 unsigned short* __restrict__ W2R,
                                                 unsigned short (&tile)[64][66]) {
    int cb = bx * 64;
    int tid = threadIdx.x;
    // phase 1: coalesced reads (consecutive threads -> consecutive cols)
    int cl = tid & 63;
    int kg = tid >> 6;
    int cp = cb + cl;
    int d = cp / DSTRIDE;
    int q = cp - d * DSTRIDE;
    int col;
    bool valid;
    if (q < 3 * LPAD) {
        int t = q / LPAD;
        int l = q - t * LPAD;
        col = t * (DIM * LS) + d * LS + l;
        valid = (l < LS);
    } else {
        int e = q - 3 * LPAD;
        col = 3 * DIM * LS + e * DIM + d;
        valid = (e < 3);
    }
#pragma unroll
    for (int kk = 0; kk < 16; kk++) {
        int k = kg * 16 + kk;
        float v = 0.0f;
        if (valid) {
            if (k < KH)       v = W2[(size_t)k * PCOLS + col];
            else if (k == KH) v = b2[col];
        }
        tile[cl][k] = f2bf(v);
    }
    __syncthreads();
    // phase 2: coalesced writes (consecutive threads -> consecutive k)
    int k = tid & 63;
    int cg = tid >> 6;
#pragma unroll
    for (int ii = 0; ii < 16; ii++) {
        int lr = cg * 16 + ii;
        W2R[(size_t)(cb + lr) * KPAD + k] = tile[lr][k];
    }
}

// ---- h = relu(cond @ W1 + b1) -> bf16 [NB][64]; h[50]=1 (bias hook) ----
static __device__ __forceinline__ void h_body(int bx, const float* __restrict__ cond,
                                              int cond_off, const float* __restrict__ W1,
                                              const float* __restrict__ b1,
                                              unsigned short* __restrict__ hb) {
    int idx = bx * 256 + threadIdx.x;   // = s*64 + k; s is wave-uniform
    int s = idx >> 6, k = idx & 63;
    float v;
    if (k < KH) {
        const float* crow = cond + (size_t)s * 64 + cond_off;
        float acc = b1[k];
#pragma unroll
        for (int j = 0; j < DIM; j++) acc = fmaf(crow[j], W1[j * KH + k], acc);
        v = fmaxf(acc, 0.0f);
    } else {
        v = (k == KH) ? 1.0f : 0.0f;
    }
    hb[idx] = f2bf(v);
}

// ---- combined: prep both subnets' W2R + h1 (all independent) ----
__global__ __launch_bounds__(256) void combo_kernel(const float* __restrict__ W2a,
                                                    const float* __restrict__ b2a,
                                                    unsigned short* __restrict__ W2Ra,
                                                    const float* __restrict__ W2b,
                                                    const float* __restrict__ b2b,
                                                    unsigned short* __restrict__ W2Rb,
                                                    const float* __restrict__ x,
                                                    const float* __restrict__ W1,
                                                    const float* __restrict__ b1,
                                                    unsigned short* __restrict__ hb) {
    __shared__ unsigned short tile[64][66];
    int b = blockIdx.x;
    if (b < 2 * PREPB) {
        if (b < PREPB) prep_body(b, W2a, b2a, W2Ra, tile);
        else           prep_body(b - PREPB, W2b, b2b, W2Rb, tile);
    } else {
        h_body(b - 2 * PREPB, x, DIM, W1, b1, hb);   // cond = x2
    }
}

__global__ __launch_bounds__(256) void h_kernel(const float* __restrict__ cond, int cond_off,
                                                const float* __restrict__ W1,
                                                const float* __restrict__ b1,
                                                unsigned short* __restrict__ hb) {
    h_body(blockIdx.x, cond, cond_off, W1, b1, hb);
}

// ---- fused p-GEMM (MFMA, B from L2 w/ 2-deep reg prefetch) + PfndELU epilogue ----
// 256-thread block = 4 waves sharing one d; each wave: 64 samples (MT=4).
__global__ __launch_bounds__(256, 4) void y_mfma(const float* __restrict__ x, int x_off,
                                                 const unsigned short* __restrict__ hb,
                                                 const unsigned short* __restrict__ W2R,
                                                 float* __restrict__ out, int out_off) {
    int tid = threadIdx.x;
    int lane = tid & 63, wave = tid >> 6;
    int c = lane & 15, g = lane >> 4;
    int d = blockIdx.y;
    int m0 = (blockIdx.x * 4 + wave) * 64;

    // A fragments: rows = samples, k = 8 contiguous bf16 at 16B*(lane>>4)
    short8 af[4][2];
#pragma unroll
    for (int mt = 0; mt < 4; mt++)
#pragma unroll
        for (int ks = 0; ks < 2; ks++)
            af[mt][ks] = *reinterpret_cast<const short8*>(
                hb + (size_t)(m0 + mt * 16 + c) * KPAD + ks * 32 + g * 8);

    float xv[4][4];
#pragma unroll
    for (int mt = 0; mt < 4; mt++)
#pragma unroll
        for (int r = 0; r < 4; r++)
            xv[mt][r] = x[(size_t)(m0 + mt * 16 + g * 4 + r) * 64 + x_off + d];

    float num[4][4] = {};
    float den[4][4] = {};
    const unsigned short* wbase = W2R + (size_t)d * DSTRIDE * KPAD;

    short8 bfA[3][2], bfB[3][2];
    auto loadB = [&](short8 (&dst)[3][2], int j) {
#pragma unroll
        for (int t = 0; t < 3; t++)
#pragma unroll
            for (int ks = 0; ks < 2; ks++)
                dst[t][ks] = *reinterpret_cast<const short8*>(
                    wbase + (size_t)(t * LPAD + j * 16 + c) * KPAD + ks * 32 + g * 8);
    };
    auto computeJ = [&](const short8 (&bf)[3][2]) {
#pragma unroll
        for (int mt = 0; mt < 4; mt++) {
            f32x4 a1 = {0.f, 0.f, 0.f, 0.f};
            f32x4 a2 = {0.f, 0.f, 0.f, 0.f};
            f32x4 a3 = {0.f, 0.f, 0.f, 0.f};
            __builtin_amdgcn_s_setprio(1);
            a1 = __builtin_amdgcn_mfma_f32_16x16x32_bf16(af[mt][0], bf[0][0], a1, 0, 0, 0);
            a1 = __builtin_amdgcn_mfma_f32_16x16x32_bf16(af[mt][1], bf[0][1], a1, 0, 0, 0);
            a2 = __builtin_amdgcn_mfma_f32_16x16x32_bf16(af[mt][0], bf[1][0], a2, 0, 0, 0);
            a2 = __builtin_amdgcn_mfma_f32_16x16x32_bf16(af[mt][1], bf[1][1], a2, 0, 0, 0);
            a3 = __builtin_amdgcn_mfma_f32_16x16x32_bf16(af[mt][0], bf[2][0], a3, 0, 0, 0);
            a3 = __builtin_amdgcn_mfma_f32_16x16x32_bf16(af[mt][1], bf[2][1], a3, 0, 0, 0);
            __builtin_amdgcn_s_setprio(0);
#pragma unroll
            for (int r = 0; r < 4; r++) {
                float m1 = a1[r], bb = a2[r], m2 = a3[r];
                float z = fmaf(xv[mt][r], m1, bb);
                float e = (z > 0.f) ? z : (__expf(z) - 1.0f);   // elu
                num[mt][r] = fmaf(e, m2, num[mt][r]);
                den[mt][r] += fmaxf(-m1 * m2, 0.f);             // relu
            }
        }
    };

    // fully-unrolled 7-step schedule, 2-deep B prefetch
    loadB(bfA, 0);
    loadB(bfB, 1);
    computeJ(bfA); loadB(bfA, 2);
    computeJ(bfB); loadB(bfB, 3);
    computeJ(bfA); loadB(bfA, 4);
    computeJ(bfB); loadB(bfB, 5);
    computeJ(bfA); loadB(bfA, 6);
    computeJ(bfB);
    computeJ(bfA);

    // tail params via 2 MFMAs: acc col 0 = bias2, col 1 = eps, col 2 = alpha
    short8 t0 = *reinterpret_cast<const short8*>(
        wbase + (size_t)(3 * LPAD + c) * KPAD + g * 8);
    short8 t1 = *reinterpret_cast<const short8*>(
        wbase + (size_t)(3 * LPAD + c) * KPAD + 32 + g * 8);
    f32x4 pt[4];
#pragma unroll
    for (int mt = 0; mt < 4; mt++) {
        f32x4 a = {0.f, 0.f, 0.f, 0.f};
        a = __builtin_amdgcn_mfma_f32_16x16x32_bf16(af[mt][0], t0, a, 0, 0, 0);
        a = __builtin_amdgcn_mfma_f32_16x16x32_bf16(af[mt][1], t1, a, 0, 0, 0);
        pt[mt] = a;
    }

    // reduce num/den over the 16 l-lanes; lane c==0 assembles params & writes
#pragma unroll
    for (int mt = 0; mt < 4; mt++)
#pragma unroll
        for (int r = 0; r < 4; r++) {
            float n = num[mt][r], dn = den[mt][r];
#pragma unroll
            for (int mask = 1; mask < 16; mask <<= 1) {
                n  += __shfl_xor(n, mask);
                dn += __shfl_xor(dn, mask);
            }
            float pb = pt[mt][r];                  // lane c=0 holds bias2
            float pe = __shfl_xor(pt[mt][r], 1);   // lane c=0 <- c=1 (eps)
            float pa = __shfl_xor(pt[mt][r], 2);   // lane c=0 <- c=2 (alpha)
            if (c == 0) {
                float sig = 0.8f / (1.0f + __expf(-pe * 0.1f));
                float y = __expf(pa * 0.1f) * (xv[mt][r] + sig * __fdividef(n, dn + 1.0f)) + pb;
                out[(size_t)(m0 + mt * 16 + g * 4 + r) * 64 + out_off + d] = y;
            }
        }
}

extern "C" void kernel_launch(void* const* d_in, const int* in_sizes, int n_in,
                              void* d_out, int out_size, void* d_ws, size_t ws_size,
                              hipStream_t stream) {
    const float* x    = (const float*)d_in[0];
    const float* s1W1 = (const float*)d_in[1];
    const float* s1b1 = (const float*)d_in[2];
    const float* s1W2 = (const float*)d_in[3];
    const float* s1b2 = (const float*)d_in[4];
    const float* s2W1 = (const float*)d_in[5];
    const float* s2b1 = (const float*)d_in[6];
    const float* s2W2 = (const float*)d_in[7];
    const float* s2b2 = (const float*)d_in[8];
    float* out = (float*)d_out;

    char* ws = (char*)d_ws;
    unsigned short* W2R1 = (unsigned short*)ws;   ws += (size_t)NCR * KPAD * 2;
    unsigned short* W2R2 = (unsigned short*)ws;   ws += (size_t)NCR * KPAD * 2;
    unsigned short* hb1  = (unsigned short*)ws;   ws += (size_t)NB * KPAD * 2;
    unsigned short* hb2  = (unsigned short*)ws;

    // dispatch 1: prep both W2R + h1 (cond = x2)
    combo_kernel<<<2 * PREPB + NB * 64 / 256, 256, 0, stream>>>(
        s1W2, s1b2, W2R1, s2W2, s2b2, W2R2, x, s1W1, s1b1, hb1);
    // dispatch 2: y1 -> out cols 0..31
    y_mfma<<<dim3(NB / 256, DIM), 256, 0, stream>>>(x, 0, hb1, W2R1, out, 0);
    // dispatch 3: h2 (cond = y1)
    h_kernel<<<NB * 64 / 256, 256, 0, stream>>>(out, 0, s2W1, s2b1, hb2);
    // dispatch 4: y2 -> out cols 32..63
    y_mfma<<<dim3(NB / 256, DIM), 256, 0, stream>>>(x, DIM, hb2, W2R2, out, DIM);
}

// Round 6
// 227.624 us; speedup vs baseline: 4.5297x; 4.5297x over previous
//
#include <hip/hip_runtime.h>
#include <hip/hip_bf16.h>

#define NB 16384
#define DIM 32
#define LS 100
#define KH 50
#define PCOLS 9696           // 3*DIM*LS + 3*DIM
#define LPAD 112             // LS padded to 7*16
#define DSTRIDE 352          // 3*LPAD + 16 tail slots (bias2, eps, alpha, 13 zero)
#define NCR (DIM * DSTRIDE)  // 11264 reordered columns
#define KPAD 64              // 50 real + 1 bias row + 13 zero
#define PREPB (NCR / 64)     // 176 prep blocks per subnet
#define HB1B (NB * 64 / 256) // 4096 h-blocks
#define XTB (NB / 64)        // 256 x-transpose blocks

typedef __attribute__((ext_vector_type(4))) float f32x4;
typedef __attribute__((ext_vector_type(8))) short short8;

static __device__ __forceinline__ unsigned short f2bf(float f) {
    __hip_bfloat16 h = __float2bfloat16(f);
    return *reinterpret_cast<unsigned short*>(&h);
}

// ---- reorder + pad + bf16-ify W2 (b2 folded as k=50 row), linear k layout ----
// W2R[row][k], row = d*352 + q; q<336: q=t*112+l (orig col t*3200+d*100+l);
// q in 336..338: tail cols 9600/9632/9664 + d (bias2, eps, alpha); rest zero.
static __device__ __forceinline__ void prep_body(int bx, const float* __restrict__ W2,
                                                 const float* __restrict__ b2,
                                                 unsigned short* __restrict__ W2R,
                                                 float* lds) {
    unsigned short (&tile)[64][66] = *reinterpret_cast<unsigned short (*)[64][66]>(lds);
    int cb = bx * 64;
    int tid = threadIdx.x;
    // phase 1: coalesced reads (consecutive threads -> consecutive cols)
    int cl = tid & 63;
    int kg = tid >> 6;
    int cp = cb + cl;
    int d = cp / DSTRIDE;
    int q = cp - d * DSTRIDE;
    int col;
    bool valid;
    if (q < 3 * LPAD) {
        int t = q / LPAD;
        int l = q - t * LPAD;
        col = t * (DIM * LS) + d * LS + l;
        valid = (l < LS);
    } else {
        int e = q - 3 * LPAD;
        col = 3 * DIM * LS + e * DIM + d;
        valid = (e < 3);
    }
#pragma unroll
    for (int kk = 0; kk < 16; kk++) {
        int k = kg * 16 + kk;
        float v = 0.0f;
        if (valid) {
            if (k < KH)       v = W2[(size_t)k * PCOLS + col];
            else if (k == KH) v = b2[col];
        }
        tile[cl][k] = f2bf(v);
    }
    __syncthreads();
    // phase 2: coalesced writes (consecutive threads -> consecutive k)
    int k = tid & 63;
    int cg = tid >> 6;
#pragma unroll
    for (int ii = 0; ii < 16; ii++) {
        int lr = cg * 16 + ii;
        W2R[(size_t)(cb + lr) * KPAD + k] = tile[lr][k];
    }
}

// ---- h = relu(cond @ W1 + b1) -> bf16 [NB][64]; h[50]=1 (bias hook) ----
static __device__ __forceinline__ void h_body(int bx, const float* __restrict__ cond,
                                              int cond_off, const float* __restrict__ W1,
                                              const float* __restrict__ b1,
                                              unsigned short* __restrict__ hb) {
    int idx = bx * 256 + threadIdx.x;   // = s*64 + k; s is wave-uniform
    int s = idx >> 6, k = idx & 63;
    float v;
    if (k < KH) {
        const float* crow = cond + (size_t)s * 64 + cond_off;
        float acc = b1[k];
#pragma unroll
        for (int j = 0; j < DIM; j++) acc = fmaf(crow[j], W1[j * KH + k], acc);
        v = fmaxf(acc, 0.0f);
    } else {
        v = (k == KH) ? 1.0f : 0.0f;
    }
    hb[idx] = f2bf(v);
}

// ---- xT[c][s] = x[s][c]: LDS tile transpose, both sides coalesced ----
static __device__ __forceinline__ void xt_body(int bx, const float* __restrict__ x,
                                               float* __restrict__ xT, float* lds) {
    float (&tile)[64][65] = *reinterpret_cast<float (*)[64][65]>(lds);
    int sb = bx * 64;
    int tid = threadIdx.x;
#pragma unroll
    for (int i = 0; i < 16; i++) {
        int idx = i * 256 + tid;
        int sl = idx >> 6, c = idx & 63;
        tile[c][sl] = x[(size_t)(sb + sl) * 64 + c];
    }
    __syncthreads();
#pragma unroll
    for (int i = 0; i < 16; i++) {
        int idx = i * 256 + tid;
        int c = idx >> 6, sl = idx & 63;
        xT[(size_t)c * NB + sb + sl] = tile[c][sl];
    }
}

// ---- combined: prep both subnets' W2R + h1 + x-transpose (all independent) ----
__global__ __launch_bounds__(256) void combo_kernel(const float* __restrict__ W2a,
                                                    const float* __restrict__ b2a,
                                                    unsigned short* __restrict__ W2Ra,
                                                    const float* __restrict__ W2b,
                                                    const float* __restrict__ b2b,
                                                    unsigned short* __restrict__ W2Rb,
                                                    const float* __restrict__ x,
                                                    const float* __restrict__ W1,
                                                    const float* __restrict__ b1,
                                                    unsigned short* __restrict__ hb,
                                                    float* __restrict__ xT) {
    __shared__ float lds[64 * 65];
    int b = blockIdx.x;
    if (b < PREPB)                 prep_body(b, W2a, b2a, W2Ra, lds);
    else if (b < 2 * PREPB)        prep_body(b - PREPB, W2b, b2b, W2Rb, lds);
    else if (b < 2 * PREPB + HB1B) h_body(b - 2 * PREPB, x, DIM, W1, b1, hb);
    else                           xt_body(b - 2 * PREPB - HB1B, x, xT, lds);
}

__global__ __launch_bounds__(256) void h_kernel(const float* __restrict__ cond, int cond_off,
                                                const float* __restrict__ W1,
                                                const float* __restrict__ b1,
                                                unsigned short* __restrict__ hb) {
    h_body(blockIdx.x, cond, cond_off, W1, b1, hb);
}

// ---- fused p-GEMM (MFMA, B from L2 w/ 2-deep reg prefetch) + PfndELU epilogue ----
// 256-thread block = 4 waves sharing one d; each wave: 64 samples (MT=4).
__global__ __launch_bounds__(256) void y_mfma(const float* __restrict__ xT, int xt_off,
                                              const unsigned short* __restrict__ hb,
                                              const unsigned short* __restrict__ W2R,
                                              float* __restrict__ out, int out_off) {
    int tid = threadIdx.x;
    int lane = tid & 63, wave = tid >> 6;
    int c = lane & 15, g = lane >> 4;
    int d = blockIdx.y;
    int m0 = (blockIdx.x * 4 + wave) * 64;

    // A fragments: rows = samples, k = 8 contiguous bf16 at 16B*(lane>>4)
    short8 af[4][2];
#pragma unroll
    for (int mt = 0; mt < 4; mt++)
#pragma unroll
        for (int ks = 0; ks < 2; ks++)
            af[mt][ks] = *reinterpret_cast<const short8*>(
                hb + (size_t)(m0 + mt * 16 + c) * KPAD + ks * 32 + g * 8);

    // x values from transposed copy: 64 consecutive floats per wave
    const float* xrow = xT + (size_t)(xt_off + d) * NB + m0;
    float xv[4][4];
#pragma unroll
    for (int mt = 0; mt < 4; mt++)
#pragma unroll
        for (int r = 0; r < 4; r++)
            xv[mt][r] = xrow[mt * 16 + g * 4 + r];

    float num[4][4] = {};
    float den[4][4] = {};
    const unsigned short* wbase = W2R + (size_t)d * DSTRIDE * KPAD;

    short8 bfA[3][2], bfB[3][2];
    auto loadB = [&](short8 (&dst)[3][2], int j) {
#pragma unroll
        for (int t = 0; t < 3; t++)
#pragma unroll
            for (int ks = 0; ks < 2; ks++)
                dst[t][ks] = *reinterpret_cast<const short8*>(
                    wbase + (size_t)(t * LPAD + j * 16 + c) * KPAD + ks * 32 + g * 8);
    };
    auto computeJ = [&](const short8 (&bf)[3][2]) {
#pragma unroll
        for (int mt = 0; mt < 4; mt++) {
            f32x4 a1 = {0.f, 0.f, 0.f, 0.f};
            f32x4 a2 = {0.f, 0.f, 0.f, 0.f};
            f32x4 a3 = {0.f, 0.f, 0.f, 0.f};
            __builtin_amdgcn_s_setprio(1);
            a1 = __builtin_amdgcn_mfma_f32_16x16x32_bf16(af[mt][0], bf[0][0], a1, 0, 0, 0);
            a1 = __builtin_amdgcn_mfma_f32_16x16x32_bf16(af[mt][1], bf[0][1], a1, 0, 0, 0);
            a2 = __builtin_amdgcn_mfma_f32_16x16x32_bf16(af[mt][0], bf[1][0], a2, 0, 0, 0);
            a2 = __builtin_amdgcn_mfma_f32_16x16x32_bf16(af[mt][1], bf[1][1], a2, 0, 0, 0);
            a3 = __builtin_amdgcn_mfma_f32_16x16x32_bf16(af[mt][0], bf[2][0], a3, 0, 0, 0);
            a3 = __builtin_amdgcn_mfma_f32_16x16x32_bf16(af[mt][1], bf[2][1], a3, 0, 0, 0);
            __builtin_amdgcn_s_setprio(0);
#pragma unroll
            for (int r = 0; r < 4; r++) {
                float m1 = a1[r], bb = a2[r], m2 = a3[r];
                float z = fmaf(xv[mt][r], m1, bb);
                float e = (z > 0.f) ? z : (__expf(z) - 1.0f);   // elu
                num[mt][r] = fmaf(e, m2, num[mt][r]);
                den[mt][r] += fmaxf(-m1 * m2, 0.f);             // relu
            }
        }
    };

    // fully-unrolled 7-step schedule, 2-deep B prefetch
    loadB(bfA, 0);
    loadB(bfB, 1);
    computeJ(bfA); loadB(bfA, 2);
    computeJ(bfB); loadB(bfB, 3);
    computeJ(bfA); loadB(bfA, 4);
    computeJ(bfB); loadB(bfB, 5);
    computeJ(bfA); loadB(bfA, 6);
    computeJ(bfB);
    computeJ(bfA);

    // tail params via 2 MFMAs: acc col 0 = bias2, col 1 = eps, col 2 = alpha
    short8 t0 = *reinterpret_cast<const short8*>(
        wbase + (size_t)(3 * LPAD + c) * KPAD + g * 8);
    short8 t1 = *reinterpret_cast<const short8*>(
        wbase + (size_t)(3 * LPAD + c) * KPAD + 32 + g * 8);
    f32x4 pt[4];
#pragma unroll
    for (int mt = 0; mt < 4; mt++) {
        f32x4 a = {0.f, 0.f, 0.f, 0.f};
        a = __builtin_amdgcn_mfma_f32_16x16x32_bf16(af[mt][0], t0, a, 0, 0, 0);
        a = __builtin_amdgcn_mfma_f32_16x16x32_bf16(af[mt][1], t1, a, 0, 0, 0);
        pt[mt] = a;
    }

    // reduce num/den over the 16 l-lanes; lane c==0 assembles params & writes
#pragma unroll
    for (int mt = 0; mt < 4; mt++)
#pragma unroll
        for (int r = 0; r < 4; r++) {
            float n = num[mt][r], dn = den[mt][r];
#pragma unroll
            for (int mask = 1; mask < 16; mask <<= 1) {
                n  += __shfl_xor(n, mask);
                dn += __shfl_xor(dn, mask);
            }
            float pb = pt[mt][r];                  // lane c=0 holds bias2
            float pe = __shfl_xor(pt[mt][r], 1);   // lane c=0 <- c=1 (eps)
            float pa = __shfl_xor(pt[mt][r], 2);   // lane c=0 <- c=2 (alpha)
            if (c == 0) {
                float sig = 0.8f / (1.0f + __expf(-pe * 0.1f));
                float y = __expf(pa * 0.1f) * (xv[mt][r] + sig * __fdividef(n, dn + 1.0f)) + pb;
                out[(size_t)(m0 + mt * 16 + g * 4 + r) * 64 + out_off + d] = y;
            }
        }
}

extern "C" void kernel_launch(void* const* d_in, const int* in_sizes, int n_in,
                              void* d_out, int out_size, void* d_ws, size_t ws_size,
                              hipStream_t stream) {
    const float* x    = (const float*)d_in[0];
    const float* s1W1 = (const float*)d_in[1];
    const float* s1b1 = (const float*)d_in[2];
    const float* s1W2 = (const float*)d_in[3];
    const float* s1b2 = (const float*)d_in[4];
    const float* s2W1 = (const float*)d_in[5];
    const float* s2b1 = (const float*)d_in[6];
    const float* s2W2 = (const float*)d_in[7];
    const float* s2b2 = (const float*)d_in[8];
    float* out = (float*)d_out;

    char* ws = (char*)d_ws;
    unsigned short* W2R1 = (unsigned short*)ws;   ws += (size_t)NCR * KPAD * 2;
    unsigned short* W2R2 = (unsigned short*)ws;   ws += (size_t)NCR * KPAD * 2;
    unsigned short* hb1  = (unsigned short*)ws;   ws += (size_t)NB * KPAD * 2;
    unsigned short* hb2  = (unsigned short*)ws;   ws += (size_t)NB * KPAD * 2;
    float* xT            = (float*)ws;            // [64][NB] f32 = 4 MB

    // dispatch 1: prep both W2R + h1 (cond = x2) + x transpose
    combo_kernel<<<2 * PREPB + HB1B + XTB, 256, 0, stream>>>(
        s1W2, s1b2, W2R1, s2W2, s2b2, W2R2, x, s1W1, s1b1, hb1, xT);
    // dispatch 2: y1 -> out cols 0..31   (x = x1 = xT rows 0..31)
    y_mfma<<<dim3(NB / 256, DIM), 256, 0, stream>>>(xT, 0, hb1, W2R1, out, 0);
    // dispatch 3: h2 (cond = y1)
    h_kernel<<<NB * 64 / 256, 256, 0, stream>>>(out, 0, s2W1, s2b1, hb2);
    // dispatch 4: y2 -> out cols 32..63  (x = x2 = xT rows 32..63)
    y_mfma<<<dim3(NB / 256, DIM), 256, 0, stream>>>(xT, DIM, hb2, W2R2, out, DIM);
}